// Round 6
// baseline (2857.305 us; speedup 1.0000x reference)
//
#include <hip/hip_runtime.h>
#include <math.h>

#define N_NODES 100000
#define BSHIFT 8
#define BNODES 256                       // nodes per bucket
#define NB ((N_NODES + BNODES - 1) / BNODES)   // 391 buckets
#define CHUNK 8192                       // edges per bucket_fill block

// ---- pass 1: per-bucket edge counts (LDS-privatized histogram) ---------------

__global__ __launch_bounds__(256) void bucket_count(const int* __restrict__ dst,
                                                    int* __restrict__ bucketCount, int E) {
    __shared__ int hist[NB];
    for (int i = threadIdx.x; i < NB; i += 256) hist[i] = 0;
    __syncthreads();
    int i = blockIdx.x * blockDim.x + threadIdx.x;
    int stride = gridDim.x * blockDim.x;
    for (int e = i; e < E; e += stride)
        atomicAdd(&hist[dst[e] >> BSHIFT], 1);
    __syncthreads();
    for (int i2 = threadIdx.x; i2 < NB; i2 += 256) {
        int c = hist[i2];
        if (c) atomicAdd(&bucketCount[i2], c);
    }
}

// ---- pass 2: exclusive scan over NB (<=512) bucket counts --------------------

__global__ __launch_bounds__(512) void bucket_scan(const int* __restrict__ bucketCount,
                                                   int* __restrict__ bucketOff,
                                                   int* __restrict__ bucketCursor, int E) {
    __shared__ int sh[512];
    int t = threadIdx.x;
    int v = (t < NB) ? bucketCount[t] : 0;
    sh[t] = v;
    __syncthreads();
    for (int d = 1; d < 512; d <<= 1) {
        int u = (t >= d) ? sh[t - d] : 0;
        __syncthreads();
        sh[t] += u;
        __syncthreads();
    }
    if (t < NB) { bucketOff[t] = sh[t] - v; bucketCursor[t] = sh[t] - v; }
    if (t == 0) bucketOff[NB] = E;
}

// ---- pass 3: block-grouped binning (counting sort per 8K chunk) --------------
// rec = src | (dst_local << 17)   (src < 2^17, dst_local < 256)

__global__ __launch_bounds__(256) void bucket_fill(const int* __restrict__ src,
                                                   const int* __restrict__ dst,
                                                   int* __restrict__ bucketCursor,
                                                   unsigned int* __restrict__ binned, int E) {
    __shared__ int hist[NB];
    __shared__ int base[NB];
    __shared__ int lcur[NB];
    __shared__ unsigned int recs[CHUNK];
    __shared__ unsigned short bkt[CHUNK];
    int t = threadIdx.x;
    for (int i = t; i < NB; i += 256) { hist[i] = 0; lcur[i] = 0; }
    __syncthreads();
    int cbase = blockIdx.x * CHUNK;
#pragma unroll
    for (int j = 0; j < CHUNK / 256; ++j) {
        int slot = t + j * 256;
        int e = cbase + slot;
        if (e < E) {
            int s = src[e];
            int d = dst[e];
            recs[slot] = (unsigned)s | ((unsigned)(d & (BNODES - 1)) << 17);
            int b = d >> BSHIFT;
            bkt[slot] = (unsigned short)b;
            atomicAdd(&hist[b], 1);
        } else {
            bkt[slot] = 0xFFFF;
        }
    }
    __syncthreads();
    for (int i = t; i < NB; i += 256) {
        int c = hist[i];
        base[i] = c ? atomicAdd(&bucketCursor[i], c) : 0;
    }
    __syncthreads();
#pragma unroll
    for (int j = 0; j < CHUNK / 256; ++j) {
        int slot = t + j * 256;
        unsigned short b = bkt[slot];
        if (b != 0xFFFF) {
            int pos = base[b] + atomicAdd(&lcur[b], 1);
            binned[pos] = recs[slot];
        }
    }
}

// ---- pass 4: per-node degree from binned recs -> dinv ------------------------

__global__ __launch_bounds__(256) void deg_dinv(const unsigned int* __restrict__ binned,
                                                const int* __restrict__ bucketOff,
                                                float* __restrict__ dinv, int n) {
    __shared__ int hist[BNODES];
    int t = threadIdx.x;
    hist[t] = 0;
    __syncthreads();
    int b = blockIdx.x;
    int rb = bucketOff[b], re = bucketOff[b + 1];
    for (int e = rb + t; e < re; e += 256)
        atomicAdd(&hist[(binned[e] >> 17) & 255], 1);
    __syncthreads();
    int g = b * BNODES + t;
    if (g < n) dinv[g] = rsqrtf((float)hist[t] + 1.0f);   // +1 = self-loop
}

// ---- per-layer dense GEMM (lin = h @ W) --------------------------------------

template<int FIN, int FOUT>
__global__ void gemm_kernel(const float* __restrict__ h, const float* __restrict__ W,
                            float* __restrict__ lin, int n) {
    __shared__ float sW[FIN * FOUT];
    for (int i = threadIdx.x; i < FIN * FOUT; i += blockDim.x) sW[i] = W[i];
    __syncthreads();
    constexpr int ROWS = 256 / FOUT;
    int f = threadIdx.x % FOUT;
    int r = threadIdx.x / FOUT;
    int row = blockIdx.x * ROWS + r;
    if (row >= n) return;
    const float* hr = h + (size_t)row * FIN;
    float acc = 0.f;
#pragma unroll
    for (int k = 0; k < FIN; ++k) acc = fmaf(hr[k], sW[k * FOUT + f], acc);
    lin[(size_t)row * FOUT + f] = acc;
}

// ---- fused aggregation: LDS accumulator per bucket ---------------------------
// h = tanh(dinv^2*lin[g] + sum_e w*lin[src] + b),  w = dinv[src]*dinv[dst]

template<int F>
__global__ __launch_bounds__(512) void bucket_aggregate(const unsigned int* __restrict__ binned,
                                                        const int* __restrict__ bucketOff,
                                                        const float* __restrict__ lin,
                                                        const float* __restrict__ dinv,
                                                        const float* __restrict__ bias,
                                                        float* __restrict__ h, int n) {
    constexpr int FS = (F >= 32) ? F : (F + 1);   // bank-spread stride for small F
    __shared__ float sacc[BNODES * FS];
    __shared__ float sdinv[BNODES];
    int t = threadIdx.x;
    int b = blockIdx.x;
    int g0 = b * BNODES;
    if (t < BNODES) {
        int g = g0 + t;
        sdinv[t] = (g < n) ? dinv[g] : 0.f;
    }
    for (int i = t; i < BNODES * FS; i += 512) sacc[i] = 0.f;
    __syncthreads();

    int rb = bucketOff[b], re = bucketOff[b + 1];
    constexpr int EPB = 512 / F;     // edges in flight per block
    int f = t % F;
    int sub = t / F;

    int e = rb + sub;
    for (; e + 3 * EPB < re; e += 4 * EPB) {
        unsigned int r0 = binned[e];
        unsigned int r1 = binned[e + EPB];
        unsigned int r2 = binned[e + 2 * EPB];
        unsigned int r3 = binned[e + 3 * EPB];
        int s0 = r0 & 0x1FFFF, d0 = (r0 >> 17) & 255;
        int s1 = r1 & 0x1FFFF, d1 = (r1 >> 17) & 255;
        int s2 = r2 & 0x1FFFF, d2 = (r2 >> 17) & 255;
        int s3 = r3 & 0x1FFFF, d3 = (r3 >> 17) & 255;
        float w0 = dinv[s0] * sdinv[d0];
        float w1 = dinv[s1] * sdinv[d1];
        float w2 = dinv[s2] * sdinv[d2];
        float w3 = dinv[s3] * sdinv[d3];
        float v0 = lin[(size_t)s0 * F + f];
        float v1 = lin[(size_t)s1 * F + f];
        float v2 = lin[(size_t)s2 * F + f];
        float v3 = lin[(size_t)s3 * F + f];
        atomicAdd(&sacc[d0 * FS + f], w0 * v0);
        atomicAdd(&sacc[d1 * FS + f], w1 * v1);
        atomicAdd(&sacc[d2 * FS + f], w2 * v2);
        atomicAdd(&sacc[d3 * FS + f], w3 * v3);
    }
    for (; e < re; e += EPB) {
        unsigned int r = binned[e];
        int s = r & 0x1FFFF, dl = (r >> 17) & 255;
        float w = dinv[s] * sdinv[dl];
        float v = lin[(size_t)s * F + f];
        atomicAdd(&sacc[dl * FS + f], w * v);
    }
    __syncthreads();

    float bf = bias[f];
    for (int nd = sub; nd < BNODES; nd += EPB) {
        int g = g0 + nd;
        if (g < n) {
            float lv = lin[(size_t)g * F + f];
            float dv = sdinv[nd];
            h[(size_t)g * F + f] = tanhf(sacc[nd * FS + f] + dv * dv * lv + bf);
        }
    }
}

// ---- classifier: out = h @ Wc + bc  (8 -> 2) ---------------------------------

__global__ void classifier_kernel(const float* __restrict__ h, const float* __restrict__ Wc,
                                  const float* __restrict__ bc, float* __restrict__ out, int n) {
    int i = blockIdx.x * blockDim.x + threadIdx.x;
    if (i >= n) return;
    const float* hr = h + (size_t)i * 8;
    float a0 = bc[0], a1 = bc[1];
#pragma unroll
    for (int k = 0; k < 8; ++k) {
        float v = hr[k];
        a0 = fmaf(v, Wc[k * 2 + 0], a0);
        a1 = fmaf(v, Wc[k * 2 + 1], a1);
    }
    out[(size_t)i * 2 + 0] = a0;
    out[(size_t)i * 2 + 1] = a1;
}

// ---- launch ------------------------------------------------------------------

extern "C" void kernel_launch(void* const* d_in, const int* in_sizes, int n_in,
                              void* d_out, int out_size, void* d_ws, size_t ws_size,
                              hipStream_t stream) {
    const float* x  = (const float*)d_in[0];
    const int*   ei = (const int*)d_in[1];
    const float* W1 = (const float*)d_in[2];  const float* b1 = (const float*)d_in[3];
    const float* W2 = (const float*)d_in[4];  const float* b2 = (const float*)d_in[5];
    const float* W3 = (const float*)d_in[6];  const float* b3 = (const float*)d_in[7];
    const float* W4 = (const float*)d_in[8];  const float* b4 = (const float*)d_in[9];
    const float* Wc = (const float*)d_in[10]; const float* bc = (const float*)d_in[11];

    float* out  = (float*)d_out;                      // [N,2]
    float* hout = out + (size_t)2 * N_NODES;          // [N,8]

    const int n = N_NODES;
    const int E = in_sizes[1] / 2;
    const int* src = ei;
    const int* dst = ei + E;

    char* w = (char*)d_ws;
    float*        dinv         = (float*)w;        w += (size_t)n * 4;
    int*          bucketCount  = (int*)w;          w += (size_t)NB * 4;
    int*          bucketOff    = (int*)w;          w += (size_t)(NB + 1) * 4;
    int*          bucketCursor = (int*)w;          w += (size_t)NB * 4;
    unsigned int* binned       = (unsigned int*)w; w += (size_t)E * 4;
    float*        lin          = (float*)w;        w += (size_t)n * 64 * 4;
    float*        hA           = (float*)w;        w += (size_t)n * 64 * 4;
    float*        hB           = (float*)w;        w += (size_t)n * 32 * 4;

    hipMemsetAsync(bucketCount, 0, NB * sizeof(int), stream);
    bucket_count<<<1024, 256, 0, stream>>>(dst, bucketCount, E);
    bucket_scan<<<1, 512, 0, stream>>>(bucketCount, bucketOff, bucketCursor, E);
    bucket_fill<<<(E + CHUNK - 1) / CHUNK, 256, 0, stream>>>(src, dst, bucketCursor, binned, E);
    deg_dinv<<<NB, 256, 0, stream>>>(binned, bucketOff, dinv, n);

    // layer 1: x[34] -> hA[64]
    gemm_kernel<34, 64><<<(n + 3) / 4, 256, 0, stream>>>(x, W1, lin, n);
    bucket_aggregate<64><<<NB, 512, 0, stream>>>(binned, bucketOff, lin, dinv, b1, hA, n);

    // layer 2: hA[64] -> hB[32]
    gemm_kernel<64, 32><<<(n + 7) / 8, 256, 0, stream>>>(hA, W2, lin, n);
    bucket_aggregate<32><<<NB, 512, 0, stream>>>(binned, bucketOff, lin, dinv, b2, hB, n);

    // layer 3: hB[32] -> hA[16]
    gemm_kernel<32, 16><<<(n + 15) / 16, 256, 0, stream>>>(hB, W3, lin, n);
    bucket_aggregate<16><<<NB, 512, 0, stream>>>(binned, bucketOff, lin, dinv, b3, hA, n);

    // layer 4: hA[16] -> hout[8]
    gemm_kernel<16, 8><<<(n + 31) / 32, 256, 0, stream>>>(hA, W4, lin, n);
    bucket_aggregate<8><<<NB, 512, 0, stream>>>(binned, bucketOff, lin, dinv, b4, hout, n);

    // classifier
    classifier_kernel<<<(n + 255) / 256, 256, 0, stream>>>(hout, Wc, bc, out, n);
}

// Round 7
// 744.129 us; speedup vs baseline: 3.8398x; 3.8398x over previous
//
#include <hip/hip_runtime.h>
#include <math.h>

#define N_NODES 100000
#define BSHIFT 8
#define BNODES 256
#define NB ((N_NODES + BNODES - 1) / BNODES)   // 391 buckets
#define CHUNK 8192

// ---- pass 1: per-bucket edge counts (LDS-privatized histogram) ---------------

__global__ __launch_bounds__(256) void bucket_count(const int* __restrict__ dst,
                                                    int* __restrict__ bucketCount, int E) {
    __shared__ int hist[NB];
    for (int i = threadIdx.x; i < NB; i += 256) hist[i] = 0;
    __syncthreads();
    int i = blockIdx.x * blockDim.x + threadIdx.x;
    int stride = gridDim.x * blockDim.x;
    for (int e = i; e < E; e += stride)
        atomicAdd(&hist[dst[e] >> BSHIFT], 1);
    __syncthreads();
    for (int i2 = threadIdx.x; i2 < NB; i2 += 256) {
        int c = hist[i2];
        if (c) atomicAdd(&bucketCount[i2], c);
    }
}

// ---- pass 2: exclusive scan over NB bucket counts ----------------------------

__global__ __launch_bounds__(512) void bucket_scan(const int* __restrict__ bucketCount,
                                                   int* __restrict__ bucketOff,
                                                   int* __restrict__ bucketCursor, int E) {
    __shared__ int sh[512];
    int t = threadIdx.x;
    int v = (t < NB) ? bucketCount[t] : 0;
    sh[t] = v;
    __syncthreads();
    for (int d = 1; d < 512; d <<= 1) {
        int u = (t >= d) ? sh[t - d] : 0;
        __syncthreads();
        sh[t] += u;
        __syncthreads();
    }
    if (t < NB) { bucketOff[t] = sh[t] - v; bucketCursor[t] = sh[t] - v; }
    if (t == 0) bucketOff[NB] = E;
}

// ---- pass 3: block-grouped binning: rec = src | (dst_local << 17) ------------

__global__ __launch_bounds__(256) void bucket_fill(const int* __restrict__ src,
                                                   const int* __restrict__ dst,
                                                   int* __restrict__ bucketCursor,
                                                   unsigned int* __restrict__ binned, int E) {
    __shared__ int hist[NB];
    __shared__ int base[NB];
    __shared__ int lcur[NB];
    __shared__ unsigned int recs[CHUNK];
    __shared__ unsigned short bkt[CHUNK];
    int t = threadIdx.x;
    for (int i = t; i < NB; i += 256) { hist[i] = 0; lcur[i] = 0; }
    __syncthreads();
    int cbase = blockIdx.x * CHUNK;
#pragma unroll
    for (int j = 0; j < CHUNK / 256; ++j) {
        int slot = t + j * 256;
        int e = cbase + slot;
        if (e < E) {
            int s = src[e];
            int d = dst[e];
            recs[slot] = (unsigned)s | ((unsigned)(d & (BNODES - 1)) << 17);
            int b = d >> BSHIFT;
            bkt[slot] = (unsigned short)b;
            atomicAdd(&hist[b], 1);
        } else {
            bkt[slot] = 0xFFFF;
        }
    }
    __syncthreads();
    for (int i = t; i < NB; i += 256) {
        int c = hist[i];
        base[i] = c ? atomicAdd(&bucketCursor[i], c) : 0;
    }
    __syncthreads();
#pragma unroll
    for (int j = 0; j < CHUNK / 256; ++j) {
        int slot = t + j * 256;
        unsigned short b = bkt[slot];
        if (b != 0xFFFF) {
            int pos = base[b] + atomicAdd(&lcur[b], 1);
            binned[pos] = recs[slot];
        }
    }
}

// ---- pass 4: per-node counts -> per-node CSR offsets + dinv ------------------

__global__ __launch_bounds__(256) void node_off_dinv(const unsigned int* __restrict__ binned,
                                                     const int* __restrict__ bucketOff,
                                                     int* __restrict__ off,
                                                     float* __restrict__ dinv, int n, int E) {
    __shared__ int hist[BNODES];
    __shared__ int sh[BNODES];
    int t = threadIdx.x;
    int b = blockIdx.x;
    hist[t] = 0;
    __syncthreads();
    int rb = bucketOff[b], re = bucketOff[b + 1];
    for (int e = rb + t; e < re; e += 256)
        atomicAdd(&hist[(binned[e] >> 17) & 255], 1);
    __syncthreads();
    int v = hist[t];
    sh[t] = v;
    __syncthreads();
    for (int d = 1; d < 256; d <<= 1) {
        int u = (t >= d) ? sh[t - d] : 0;
        __syncthreads();
        sh[t] += u;
        __syncthreads();
    }
    int g = b * BNODES + t;
    if (g < n) {
        off[g] = rb + sh[t] - v;             // exclusive within bucket + bucket base
        dinv[g] = rsqrtf((float)v + 1.0f);   // +1 = self-loop
    }
    if (b == NB - 1 && t == 0) off[n] = E;
}

// ---- pass 5: node-sort within bucket: srcs[] ordered by dst node -------------

__global__ __launch_bounds__(256) void node_sort(const unsigned int* __restrict__ binned,
                                                 const int* __restrict__ bucketOff,
                                                 const int* __restrict__ off,
                                                 int* __restrict__ srcs, int n) {
    __shared__ int lcur[BNODES];
    int t = threadIdx.x;
    int b = blockIdx.x;
    int g = b * BNODES + t;
    lcur[t] = (g < n) ? off[g] : 0;
    __syncthreads();
    int rb = bucketOff[b], re = bucketOff[b + 1];
    for (int e = rb + t; e < re; e += 256) {
        unsigned int r = binned[e];
        int dl = (r >> 17) & 255;
        int pos = atomicAdd(&lcur[dl], 1);
        srcs[pos] = (int)(r & 0x1FFFF);
    }
}

// ---- layer 1 aggregation in 34-dim input space: aggx = (A_norm) * x ----------
// 32 lanes per node; lanes 0,1 also cover features 32,33.

__global__ __launch_bounds__(256) void gather_x(const int* __restrict__ off,
                                                const int* __restrict__ srcs,
                                                const float* __restrict__ x,
                                                const float* __restrict__ dinv,
                                                float* __restrict__ aggx, int n) {
    int g = blockIdx.x * 8 + threadIdx.x / 32;
    int f = threadIdx.x & 31;
    if (g >= n) return;
    int rb = off[g], re = off[g + 1];
    float dv = dinv[g];
    const float* xg = x + (size_t)g * 34;
    float acc0 = dv * dv * xg[f];
    float acc1 = (f < 2) ? dv * dv * xg[32 + f] : 0.f;
    for (int e = rb; e < re; ++e) {
        int s = srcs[e];
        float w = dinv[s] * dv;
        const float* xs = x + (size_t)s * 34;
        acc0 = fmaf(w, xs[f], acc0);
        if (f < 2) acc1 = fmaf(w, xs[32 + f], acc1);
    }
    float* og = aggx + (size_t)g * 34;
    og[f] = acc0;
    if (f < 2) og[32 + f] = acc1;
}

// ---- dense GEMMs -------------------------------------------------------------

template<int FIN, int FOUT, bool TANH>
__global__ void gemm_kernel(const float* __restrict__ h, const float* __restrict__ W,
                            const float* __restrict__ bias, float* __restrict__ lin, int n) {
    __shared__ float sW[FIN * FOUT];
    for (int i = threadIdx.x; i < FIN * FOUT; i += blockDim.x) sW[i] = W[i];
    __syncthreads();
    constexpr int ROWS = 256 / FOUT;
    int f = threadIdx.x % FOUT;
    int r = threadIdx.x / FOUT;
    int row = blockIdx.x * ROWS + r;
    if (row >= n) return;
    const float* hr = h + (size_t)row * FIN;
    float acc = 0.f;
#pragma unroll
    for (int k = 0; k < FIN; ++k) acc = fmaf(hr[k], sW[k * FOUT + f], acc);
    if (TANH) acc = tanhf(acc + bias[f]);
    lin[(size_t)row * FOUT + f] = acc;
}

// ---- fused aggregation + bias + tanh (layers 2-4, post-GEMM space) -----------

template<int F>
__global__ void gather_tanh(const int* __restrict__ off, const int* __restrict__ srcs,
                            const float* __restrict__ lin, const float* __restrict__ dinv,
                            const float* __restrict__ bias, float* __restrict__ h, int n) {
    constexpr int GPB = 256 / F;
    int g = blockIdx.x * GPB + threadIdx.x / F;
    int f = threadIdx.x % F;
    if (g >= n) return;
    int rb = off[g], re = off[g + 1];
    float dv = dinv[g];
    float acc = dv * dv * lin[(size_t)g * F + f];
#pragma unroll 2
    for (int e = rb; e < re; ++e) {
        int s = srcs[e];
        float w = dinv[s] * dv;
        acc = fmaf(w, lin[(size_t)s * F + f], acc);
    }
    h[(size_t)g * F + f] = tanhf(acc + bias[f]);
}

// ---- classifier: out = h @ Wc + bc  (8 -> 2) ---------------------------------

__global__ void classifier_kernel(const float* __restrict__ h, const float* __restrict__ Wc,
                                  const float* __restrict__ bc, float* __restrict__ out, int n) {
    int i = blockIdx.x * blockDim.x + threadIdx.x;
    if (i >= n) return;
    const float* hr = h + (size_t)i * 8;
    float a0 = bc[0], a1 = bc[1];
#pragma unroll
    for (int k = 0; k < 8; ++k) {
        float v = hr[k];
        a0 = fmaf(v, Wc[k * 2 + 0], a0);
        a1 = fmaf(v, Wc[k * 2 + 1], a1);
    }
    out[(size_t)i * 2 + 0] = a0;
    out[(size_t)i * 2 + 1] = a1;
}

// ---- launch ------------------------------------------------------------------

extern "C" void kernel_launch(void* const* d_in, const int* in_sizes, int n_in,
                              void* d_out, int out_size, void* d_ws, size_t ws_size,
                              hipStream_t stream) {
    const float* x  = (const float*)d_in[0];
    const int*   ei = (const int*)d_in[1];
    const float* W1 = (const float*)d_in[2];  const float* b1 = (const float*)d_in[3];
    const float* W2 = (const float*)d_in[4];  const float* b2 = (const float*)d_in[5];
    const float* W3 = (const float*)d_in[6];  const float* b3 = (const float*)d_in[7];
    const float* W4 = (const float*)d_in[8];  const float* b4 = (const float*)d_in[9];
    const float* Wc = (const float*)d_in[10]; const float* bc = (const float*)d_in[11];

    float* out  = (float*)d_out;                      // [N,2]
    float* hout = out + (size_t)2 * N_NODES;          // [N,8]

    const int n = N_NODES;
    const int E = in_sizes[1] / 2;
    const int* src = ei;
    const int* dst = ei + E;

    char* w = (char*)d_ws;
    float*        dinv         = (float*)w;        w += (size_t)n * 4;
    int*          bucketCount  = (int*)w;          w += (size_t)NB * 4;
    int*          bucketOff    = (int*)w;          w += (size_t)(NB + 1) * 4;
    int*          bucketCursor = (int*)w;          w += (size_t)NB * 4;
    int*          off          = (int*)w;          w += (size_t)(n + 1) * 4;
    unsigned int* binned       = (unsigned int*)w; w += (size_t)E * 4;
    int*          srcs         = (int*)w;          w += (size_t)E * 4;
    float*        aggx         = (float*)w;        w += (size_t)n * 34 * 4;
    float*        lin          = (float*)w;        w += (size_t)n * 64 * 4;
    float*        hA           = (float*)w;        w += (size_t)n * 64 * 4;
    float*        hB           = (float*)w;        w += (size_t)n * 32 * 4;

    hipMemsetAsync(bucketCount, 0, NB * sizeof(int), stream);
    bucket_count<<<1024, 256, 0, stream>>>(dst, bucketCount, E);
    bucket_scan<<<1, 512, 0, stream>>>(bucketCount, bucketOff, bucketCursor, E);
    bucket_fill<<<(E + CHUNK - 1) / CHUNK, 256, 0, stream>>>(src, dst, bucketCursor, binned, E);
    node_off_dinv<<<NB, 256, 0, stream>>>(binned, bucketOff, off, dinv, n, E);
    node_sort<<<NB, 256, 0, stream>>>(binned, bucketOff, off, srcs, n);

    // layer 1: aggregate in 34-dim input space, then fused GEMM+bias+tanh
    gather_x<<<(n + 7) / 8, 256, 0, stream>>>(off, srcs, x, dinv, aggx, n);
    gemm_kernel<34, 64, true><<<(n + 3) / 4, 256, 0, stream>>>(aggx, W1, b1, hA, n);

    // layer 2: hA[64] -> hB[32]
    gemm_kernel<64, 32, false><<<(n + 7) / 8, 256, 0, stream>>>(hA, W2, b2, lin, n);
    gather_tanh<32><<<(n + 7) / 8, 256, 0, stream>>>(off, srcs, lin, dinv, b2, hB, n);

    // layer 3: hB[32] -> hA[16]
    gemm_kernel<32, 16, false><<<(n + 15) / 16, 256, 0, stream>>>(hB, W3, b3, lin, n);
    gather_tanh<16><<<(n + 15) / 16, 256, 0, stream>>>(off, srcs, lin, dinv, b3, hA, n);

    // layer 4: hA[16] -> hout[8]
    gemm_kernel<16, 8, false><<<(n + 31) / 32, 256, 0, stream>>>(hA, W4, b4, lin, n);
    gather_tanh<8><<<(n + 31) / 32, 256, 0, stream>>>(off, srcs, lin, dinv, b4, hout, n);

    // classifier
    classifier_kernel<<<(n + 255) / 256, 256, 0, stream>>>(hout, Wc, bc, out, n);
}

// Round 8
// 498.631 us; speedup vs baseline: 5.7303x; 1.4923x over previous
//
#include <hip/hip_runtime.h>
#include <math.h>

#define N_NODES 100000
#define BSHIFT 8
#define BNODES 256
#define NB ((N_NODES + BNODES - 1) / BNODES)   // 391 buckets
#define CHUNK 8192

// ---- bf16 helpers (pack with round-to-nearest-even, unpack via bit ops) ------

__device__ __forceinline__ unsigned short f2bf(float x) {
    unsigned u = __float_as_uint(x);
    u += 0x7FFFu + ((u >> 16) & 1u);
    return (unsigned short)(u >> 16);
}
__device__ __forceinline__ unsigned pack2(float a, float b) {
    return (unsigned)f2bf(a) | ((unsigned)f2bf(b) << 16);
}
__device__ __forceinline__ float bflo(unsigned u) { return __uint_as_float(u << 16); }
__device__ __forceinline__ float bfhi(unsigned u) { return __uint_as_float(u & 0xFFFF0000u); }

// ---- pass 1: per-bucket edge counts (LDS-privatized histogram) ---------------

__global__ __launch_bounds__(256) void bucket_count(const int* __restrict__ dst,
                                                    int* __restrict__ bucketCount, int E) {
    __shared__ int hist[NB];
    for (int i = threadIdx.x; i < NB; i += 256) hist[i] = 0;
    __syncthreads();
    int i = blockIdx.x * blockDim.x + threadIdx.x;
    int stride = gridDim.x * blockDim.x;
    for (int e = i; e < E; e += stride)
        atomicAdd(&hist[dst[e] >> BSHIFT], 1);
    __syncthreads();
    for (int i2 = threadIdx.x; i2 < NB; i2 += 256) {
        int c = hist[i2];
        if (c) atomicAdd(&bucketCount[i2], c);
    }
}

// ---- pass 2: exclusive scan over NB bucket counts ----------------------------

__global__ __launch_bounds__(512) void bucket_scan(const int* __restrict__ bucketCount,
                                                   int* __restrict__ bucketOff,
                                                   int* __restrict__ bucketCursor, int E) {
    __shared__ int sh[512];
    int t = threadIdx.x;
    int v = (t < NB) ? bucketCount[t] : 0;
    sh[t] = v;
    __syncthreads();
    for (int d = 1; d < 512; d <<= 1) {
        int u = (t >= d) ? sh[t - d] : 0;
        __syncthreads();
        sh[t] += u;
        __syncthreads();
    }
    if (t < NB) { bucketOff[t] = sh[t] - v; bucketCursor[t] = sh[t] - v; }
    if (t == 0) bucketOff[NB] = E;
}

// ---- pass 3: block-grouped binning: rec = src | (dst_local << 17) ------------

__global__ __launch_bounds__(256) void bucket_fill(const int* __restrict__ src,
                                                   const int* __restrict__ dst,
                                                   int* __restrict__ bucketCursor,
                                                   unsigned int* __restrict__ binned, int E) {
    __shared__ int hist[NB];
    __shared__ int base[NB];
    __shared__ int lcur[NB];
    __shared__ unsigned int recs[CHUNK];
    __shared__ unsigned short bkt[CHUNK];
    int t = threadIdx.x;
    for (int i = t; i < NB; i += 256) { hist[i] = 0; lcur[i] = 0; }
    __syncthreads();
    int cbase = blockIdx.x * CHUNK;
#pragma unroll
    for (int j = 0; j < CHUNK / 256; ++j) {
        int slot = t + j * 256;
        int e = cbase + slot;
        if (e < E) {
            int s = src[e];
            int d = dst[e];
            recs[slot] = (unsigned)s | ((unsigned)(d & (BNODES - 1)) << 17);
            int b = d >> BSHIFT;
            bkt[slot] = (unsigned short)b;
            atomicAdd(&hist[b], 1);
        } else {
            bkt[slot] = 0xFFFF;
        }
    }
    __syncthreads();
    for (int i = t; i < NB; i += 256) {
        int c = hist[i];
        base[i] = c ? atomicAdd(&bucketCursor[i], c) : 0;
    }
    __syncthreads();
#pragma unroll
    for (int j = 0; j < CHUNK / 256; ++j) {
        int slot = t + j * 256;
        unsigned short b = bkt[slot];
        if (b != 0xFFFF) {
            int pos = base[b] + atomicAdd(&lcur[b], 1);
            binned[pos] = recs[slot];
        }
    }
}

// ---- pass 4: per-node counts -> per-node CSR offsets + dinv ------------------

__global__ __launch_bounds__(256) void node_off_dinv(const unsigned int* __restrict__ binned,
                                                     const int* __restrict__ bucketOff,
                                                     int* __restrict__ off,
                                                     float* __restrict__ dinv, int n, int E) {
    __shared__ int hist[BNODES];
    __shared__ int sh[BNODES];
    int t = threadIdx.x;
    int b = blockIdx.x;
    hist[t] = 0;
    __syncthreads();
    int rb = bucketOff[b], re = bucketOff[b + 1];
    for (int e = rb + t; e < re; e += 256)
        atomicAdd(&hist[(binned[e] >> 17) & 255], 1);
    __syncthreads();
    int v = hist[t];
    sh[t] = v;
    __syncthreads();
    for (int d = 1; d < 256; d <<= 1) {
        int u = (t >= d) ? sh[t - d] : 0;
        __syncthreads();
        sh[t] += u;
        __syncthreads();
    }
    int g = b * BNODES + t;
    if (g < n) {
        off[g] = rb + sh[t] - v;
        dinv[g] = rsqrtf((float)v + 1.0f);   // +1 = self-loop
    }
    if (b == NB - 1 && t == 0) off[n] = E;
}

// ---- pass 5: node-sort within bucket: srcs[] ordered by dst node -------------

__global__ __launch_bounds__(256) void node_sort(const unsigned int* __restrict__ binned,
                                                 const int* __restrict__ bucketOff,
                                                 const int* __restrict__ off,
                                                 int* __restrict__ srcs, int n) {
    __shared__ int lcur[BNODES];
    int t = threadIdx.x;
    int b = blockIdx.x;
    int g = b * BNODES + t;
    lcur[t] = (g < n) ? off[g] : 0;
    __syncthreads();
    int rb = bucketOff[b], re = bucketOff[b + 1];
    for (int e = rb + t; e < re; e += 256) {
        unsigned int r = binned[e];
        int dl = (r >> 17) & 255;
        int pos = atomicAdd(&lcur[dl], 1);
        srcs[pos] = (int)(r & 0x1FFFF);
    }
}

// ---- pack x to bf16: main [n][16] u32 (feat 0-31, 64B rows), tail [n] u32 ----

__global__ void x_pack(const float* __restrict__ x, unsigned* __restrict__ xm,
                       unsigned* __restrict__ xt, int n) {
    int i = blockIdx.x * blockDim.x + threadIdx.x;
    if (i >= n) return;
    const float2* xr = (const float2*)(x + (size_t)i * 34);
    unsigned* om = xm + (size_t)i * 16;
#pragma unroll
    for (int j = 0; j < 16; ++j) { float2 v = xr[j]; om[j] = pack2(v.x, v.y); }
    float2 v = xr[16];
    xt[i] = pack2(v.x, v.y);
}

// ---- layer-1 aggregation (input space, bf16 gather, fp32 accum) --------------
// 16 lanes per node; lane f handles features 2f,2f+1; lane 0 also 32,33.

__global__ __launch_bounds__(256) void gather_x_bf16(const int* __restrict__ off,
        const int* __restrict__ srcs, const unsigned* __restrict__ xm,
        const unsigned* __restrict__ xt, const float* __restrict__ dinv,
        float* __restrict__ aggx, int n) {
    int g = blockIdx.x * 16 + (threadIdx.x >> 4);
    int f = threadIdx.x & 15;
    if (g >= n) return;
    int rb = off[g], re = off[g + 1];
    float dv = dinv[g];
    unsigned ug = xm[(size_t)g * 16 + f];
    float a0 = dv * dv * bflo(ug), a1 = dv * dv * bfhi(ug);
    float a2 = 0.f, a3 = 0.f;
    if (f == 0) { unsigned t = xt[g]; a2 = dv * dv * bflo(t); a3 = dv * dv * bfhi(t); }
    int e = rb;
    for (; e + 4 <= re; e += 4) {
        int s0 = srcs[e], s1 = srcs[e + 1], s2 = srcs[e + 2], s3 = srcs[e + 3];
        unsigned u0 = xm[(size_t)s0 * 16 + f], u1 = xm[(size_t)s1 * 16 + f];
        unsigned u2 = xm[(size_t)s2 * 16 + f], u3 = xm[(size_t)s3 * 16 + f];
        float w0 = dinv[s0] * dv, w1 = dinv[s1] * dv, w2 = dinv[s2] * dv, w3 = dinv[s3] * dv;
        a0 = fmaf(w0, bflo(u0), a0); a1 = fmaf(w0, bfhi(u0), a1);
        a0 = fmaf(w1, bflo(u1), a0); a1 = fmaf(w1, bfhi(u1), a1);
        a0 = fmaf(w2, bflo(u2), a0); a1 = fmaf(w2, bfhi(u2), a1);
        a0 = fmaf(w3, bflo(u3), a0); a1 = fmaf(w3, bfhi(u3), a1);
        if (f == 0) {
            unsigned t0 = xt[s0], t1 = xt[s1], t2 = xt[s2], t3 = xt[s3];
            a2 = fmaf(w0, bflo(t0), a2); a3 = fmaf(w0, bfhi(t0), a3);
            a2 = fmaf(w1, bflo(t1), a2); a3 = fmaf(w1, bfhi(t1), a3);
            a2 = fmaf(w2, bflo(t2), a2); a3 = fmaf(w2, bfhi(t2), a3);
            a2 = fmaf(w3, bflo(t3), a2); a3 = fmaf(w3, bfhi(t3), a3);
        }
    }
    for (; e < re; ++e) {
        int s = srcs[e];
        unsigned u = xm[(size_t)s * 16 + f];
        float w = dinv[s] * dv;
        a0 = fmaf(w, bflo(u), a0); a1 = fmaf(w, bfhi(u), a1);
        if (f == 0) {
            unsigned t = xt[s];
            a2 = fmaf(w, bflo(t), a2); a3 = fmaf(w, bfhi(t), a3);
        }
    }
    float2* og = (float2*)(aggx + (size_t)g * 34);
    og[f] = make_float2(a0, a1);
    if (f == 0) og[16] = make_float2(a2, a3);
}

// ---- layer-1 GEMM + bias + tanh (fp32 in/out) --------------------------------

template<int FIN, int FOUT>
__global__ void gemm_tanh(const float* __restrict__ h, const float* __restrict__ W,
                          const float* __restrict__ bias, float* __restrict__ o, int n) {
    __shared__ float sW[FIN * FOUT];
    for (int i = threadIdx.x; i < FIN * FOUT; i += blockDim.x) sW[i] = W[i];
    __syncthreads();
    constexpr int ROWS = 256 / FOUT;
    int f = threadIdx.x % FOUT;
    int r = threadIdx.x / FOUT;
    int row = blockIdx.x * ROWS + r;
    if (row >= n) return;
    const float* hr = h + (size_t)row * FIN;
    float acc = 0.f;
#pragma unroll
    for (int k = 0; k < FIN; ++k) acc = fmaf(hr[k], sW[k * FOUT + f], acc);
    o[(size_t)row * FOUT + f] = tanhf(acc + bias[f]);
}

// ---- layers 2-4 GEMM, emits packed bf16 (2 features/thread) ------------------

template<int FIN, int FOUT>
__global__ void gemm_pack(const float* __restrict__ h, const float* __restrict__ W,
                          unsigned* __restrict__ linh, int n) {
    __shared__ float sW[FIN * FOUT];
    for (int i = threadIdx.x; i < FIN * FOUT; i += blockDim.x) sW[i] = W[i];
    __syncthreads();
    constexpr int NL = FOUT / 2;
    constexpr int ROWS = 256 / NL;
    int f = threadIdx.x % NL;
    int r = threadIdx.x / NL;
    int row = blockIdx.x * ROWS + r;
    if (row >= n) return;
    const float* hr = h + (size_t)row * FIN;
    float a0 = 0.f, a1 = 0.f;
#pragma unroll
    for (int k = 0; k < FIN; ++k) {
        float v = hr[k];
        a0 = fmaf(v, sW[k * FOUT + 2 * f], a0);
        a1 = fmaf(v, sW[k * FOUT + 2 * f + 1], a1);
    }
    linh[(size_t)row * NL + f] = pack2(a0, a1);
}

// ---- fused bf16 gather + bias + tanh (layers 2-4) ----------------------------

template<int F>
__global__ __launch_bounds__(256) void gather_bf16(const int* __restrict__ off,
        const int* __restrict__ srcs, const unsigned* __restrict__ linh,
        const float* __restrict__ dinv, const float* __restrict__ bias,
        float* __restrict__ h, int n) {
    constexpr int NL = F / 2;
    int g = blockIdx.x * (256 / NL) + threadIdx.x / NL;
    int f = threadIdx.x % NL;
    if (g >= n) return;
    int rb = off[g], re = off[g + 1];
    float dv = dinv[g];
    unsigned ug = linh[(size_t)g * NL + f];
    float a0 = dv * dv * bflo(ug), a1 = dv * dv * bfhi(ug);
    int e = rb;
    for (; e + 4 <= re; e += 4) {
        int s0 = srcs[e], s1 = srcs[e + 1], s2 = srcs[e + 2], s3 = srcs[e + 3];
        unsigned u0 = linh[(size_t)s0 * NL + f], u1 = linh[(size_t)s1 * NL + f];
        unsigned u2 = linh[(size_t)s2 * NL + f], u3 = linh[(size_t)s3 * NL + f];
        float w0 = dinv[s0] * dv, w1 = dinv[s1] * dv, w2 = dinv[s2] * dv, w3 = dinv[s3] * dv;
        a0 = fmaf(w0, bflo(u0), a0); a1 = fmaf(w0, bfhi(u0), a1);
        a0 = fmaf(w1, bflo(u1), a0); a1 = fmaf(w1, bfhi(u1), a1);
        a0 = fmaf(w2, bflo(u2), a0); a1 = fmaf(w2, bfhi(u2), a1);
        a0 = fmaf(w3, bflo(u3), a0); a1 = fmaf(w3, bfhi(u3), a1);
    }
    for (; e < re; ++e) {
        int s = srcs[e];
        unsigned u = linh[(size_t)s * NL + f];
        float w = dinv[s] * dv;
        a0 = fmaf(w, bflo(u), a0); a1 = fmaf(w, bfhi(u), a1);
    }
    a0 = tanhf(a0 + bias[2 * f]);
    a1 = tanhf(a1 + bias[2 * f + 1]);
    *(float2*)(h + (size_t)g * F + 2 * f) = make_float2(a0, a1);
}

// ---- classifier: out = h @ Wc + bc  (8 -> 2) ---------------------------------

__global__ void classifier_kernel(const float* __restrict__ h, const float* __restrict__ Wc,
                                  const float* __restrict__ bc, float* __restrict__ out, int n) {
    int i = blockIdx.x * blockDim.x + threadIdx.x;
    if (i >= n) return;
    const float* hr = h + (size_t)i * 8;
    float a0 = bc[0], a1 = bc[1];
#pragma unroll
    for (int k = 0; k < 8; ++k) {
        float v = hr[k];
        a0 = fmaf(v, Wc[k * 2 + 0], a0);
        a1 = fmaf(v, Wc[k * 2 + 1], a1);
    }
    out[(size_t)i * 2 + 0] = a0;
    out[(size_t)i * 2 + 1] = a1;
}

// ---- launch ------------------------------------------------------------------

static inline char* alignp(char* p) {
    return (char*)(((uintptr_t)p + 15) & ~(uintptr_t)15);
}

extern "C" void kernel_launch(void* const* d_in, const int* in_sizes, int n_in,
                              void* d_out, int out_size, void* d_ws, size_t ws_size,
                              hipStream_t stream) {
    const float* x  = (const float*)d_in[0];
    const int*   ei = (const int*)d_in[1];
    const float* W1 = (const float*)d_in[2];  const float* b1 = (const float*)d_in[3];
    const float* W2 = (const float*)d_in[4];  const float* b2 = (const float*)d_in[5];
    const float* W3 = (const float*)d_in[6];  const float* b3 = (const float*)d_in[7];
    const float* W4 = (const float*)d_in[8];  const float* b4 = (const float*)d_in[9];
    const float* Wc = (const float*)d_in[10]; const float* bc = (const float*)d_in[11];

    float* out  = (float*)d_out;                      // [N,2]
    float* hout = out + (size_t)2 * N_NODES;          // [N,8]

    const int n = N_NODES;
    const int E = in_sizes[1] / 2;
    const int* src = ei;
    const int* dst = ei + E;

    char* w = (char*)d_ws;
    float*        dinv         = (float*)w;        w = alignp(w + (size_t)n * 4);
    int*          bucketCount  = (int*)w;          w = alignp(w + (size_t)NB * 4);
    int*          bucketOff    = (int*)w;          w = alignp(w + (size_t)(NB + 1) * 4);
    int*          bucketCursor = (int*)w;          w = alignp(w + (size_t)NB * 4);
    int*          off          = (int*)w;          w = alignp(w + (size_t)(n + 1) * 4);
    unsigned int* binned       = (unsigned int*)w; w = alignp(w + (size_t)E * 4);
    int*          srcs         = (int*)w;          w = alignp(w + (size_t)E * 4);
    unsigned int* xm           = (unsigned int*)w; w = alignp(w + (size_t)n * 16 * 4);
    unsigned int* xt           = (unsigned int*)w; w = alignp(w + (size_t)n * 4);
    float*        aggx         = (float*)w;        w = alignp(w + (size_t)n * 34 * 4);
    float*        hA           = (float*)w;        w = alignp(w + (size_t)n * 64 * 4);
    float*        hB           = (float*)w;        w = alignp(w + (size_t)n * 32 * 4);
    unsigned int* linh         = (unsigned int*)w; w = alignp(w + (size_t)n * 16 * 4);

    hipMemsetAsync(bucketCount, 0, NB * sizeof(int), stream);
    bucket_count<<<1024, 256, 0, stream>>>(dst, bucketCount, E);
    bucket_scan<<<1, 512, 0, stream>>>(bucketCount, bucketOff, bucketCursor, E);
    bucket_fill<<<(E + CHUNK - 1) / CHUNK, 256, 0, stream>>>(src, dst, bucketCursor, binned, E);
    node_off_dinv<<<NB, 256, 0, stream>>>(binned, bucketOff, off, dinv, n, E);
    node_sort<<<NB, 256, 0, stream>>>(binned, bucketOff, off, srcs, n);
    x_pack<<<(n + 255) / 256, 256, 0, stream>>>(x, xm, xt, n);

    // layer 1: aggregate in 34-dim input space (bf16), then fused GEMM+bias+tanh
    gather_x_bf16<<<(n + 15) / 16, 256, 0, stream>>>(off, srcs, xm, xt, dinv, aggx, n);
    gemm_tanh<34, 64><<<(n + 3) / 4, 256, 0, stream>>>(aggx, W1, b1, hA, n);

    // layer 2: hA[64] -> hB[32]
    gemm_pack<64, 32><<<(n + 15) / 16, 256, 0, stream>>>(hA, W2, linh, n);
    gather_bf16<32><<<(n + 15) / 16, 256, 0, stream>>>(off, srcs, linh, dinv, b2, hB, n);

    // layer 3: hB[32] -> hA[16] (reuse hA)
    gemm_pack<32, 16><<<(n + 31) / 32, 256, 0, stream>>>(hB, W3, linh, n);
    gather_bf16<16><<<(n + 31) / 32, 256, 0, stream>>>(off, srcs, linh, dinv, b3, hA, n);

    // layer 4: hA[16] -> hout[8]
    gemm_pack<16, 8><<<(n + 63) / 64, 256, 0, stream>>>(hA, W4, linh, n);
    gather_bf16<8><<<(n + 63) / 64, 256, 0, stream>>>(off, srcs, linh, dinv, b4, hout, n);

    // classifier
    classifier_kernel<<<(n + 255) / 256, 256, 0, stream>>>(hout, Wc, bc, out, n);
}